// Round 1
// baseline (235.013 us; speedup 1.0000x reference)
//
#include <hip/hip_runtime.h>
#include <hip/hip_bf16.h>
#include <math.h>

// SoAP: x[64,16384,16] -> cov[64,16,16] -> logm -> sign*|.|^p -> FC(256) -> L2 normalize
// R6: fuse cov + finish into ONE kernel via per-batch split-K semaphore.
//     Cov main loop identical to R5 (linear float4 loads, wave-private LDS
//     transpose, hi/lo bf16 3-MFMA chain). Each block writes its partial,
//     __threadfence(), atomicAdd on a per-batch counter; the 16th arriver
//     runs the finish (logm/pow/FC/normalize) inline, reusing its LDS slab.
//     Removes the second launch + the all-1024-blocks dependency: per-batch
//     finish overlaps other batches' cov tails.
//     Horner uses ping-pong buffers: 1 barrier/iter instead of 2.

#define B_BATCH 64
#define N_PTS   16384
#define BLOCKS_PER_BATCH 16
#define PTS_PER_WAVE 256
#define SLICE 2176                      // dwords per wave slice (128 pts, padded)
#define PART_FLOATS (B_BATCH * BLOCKS_PER_BATCH * 256)

typedef short bf16x8 __attribute__((ext_vector_type(8)));
typedef float f32x4  __attribute__((ext_vector_type(4)));

__device__ __forceinline__ int lds_off(int p, int f) {   // p in [0,128), f in [0,16)
    return p * 16 + (p >> 3) * 8 + f;
}

__global__ __launch_bounds__(256, 4) void soap_fused_kernel(
    const float* __restrict__ x, const float* __restrict__ W,
    const float* __restrict__ bias, const float* __restrict__ p_ptr,
    float* __restrict__ part, unsigned int* __restrict__ ctr,
    float* __restrict__ out)
{
    __shared__ float sLds[4 * SLICE];              // 34816 B, wave-private slices
    __shared__ float sRed[3 * 320];                // 3840 B
    __shared__ unsigned sIsLast;

    const int t     = threadIdx.x;
    const int lane  = t & 63;
    const int wave  = t >> 6;
    const int b     = blockIdx.x >> 4;
    const int split = (blockIdx.x & 15) * 4 + wave;   // 0..63
    const int feat  = lane & 15;
    const int pgrp  = lane >> 4;

    const float4* __restrict__ xw = (const float4*)(x
        + ((size_t)b * N_PTS + (size_t)split * PTS_PER_WAVE) * 16);
    float* slice = &sLds[wave * SLICE];

    // issue all 16 linear 1-KB wave loads up front (16 KB in flight per wave)
    float4 reg[16];
#pragma unroll
    for (int j = 0; j < 16; ++j) reg[j] = xw[j * 64 + lane];

    f32x4 acc = {0.f, 0.f, 0.f, 0.f};

#pragma unroll
    for (int h = 0; h < 2; ++h) {
        // stage 128 points into the wave slice (b128 writes, 16B-aligned)
#pragma unroll
        for (int j = 0; j < 8; ++j) {
            const int q = j * 64 + lane;           // float4 index within half
            const int p = q >> 2, c = q & 3;
            *(float4*)&slice[lds_off(p, c * 4)] = reg[h * 8 + j];
        }
        // consume: 4 chunks of 32 points
#pragma unroll
        for (int c32 = 0; c32 < 4; ++c32) {
            bf16x8 H, L;
#pragma unroll
            for (int j = 0; j < 8; ++j) {
                const int p = c32 * 32 + pgrp * 8 + j;
                const float v = slice[lds_off(p, feat)];
                const unsigned u = __builtin_bit_cast(unsigned, v);
                H[j] = (short)(u >> 16);
                const float hf = __builtin_bit_cast(float, u & 0xFFFF0000u);
                const float lo = v - hf;
                L[j] = (short)(__builtin_bit_cast(unsigned, lo) >> 16);
            }
            acc = __builtin_amdgcn_mfma_f32_16x16x32_bf16(H, H, acc, 0, 0, 0);
            acc = __builtin_amdgcn_mfma_f32_16x16x32_bf16(H, L, acc, 0, 0, 0);
            acc = __builtin_amdgcn_mfma_f32_16x16x32_bf16(L, H, acc, 0, 0, 0);
        }
    }

    // intra-block reduction: waves 1..3 park acc, wave 0 sums and writes.
    // transposed (feat-major) store; cov symmetric so orientation is harmless.
    if (wave > 0) {
        float* sp = &sRed[(wave - 1) * 320 + feat * 20 + pgrp * 4];
#pragma unroll
        for (int r = 0; r < 4; ++r) sp[r] = acc[r];
    }
    __syncthreads();
    if (wave == 0) {
        float* op = part + (size_t)blockIdx.x * 256 + feat * 16 + pgrp * 4;
        const int o = feat * 20 + pgrp * 4;
#pragma unroll
        for (int r = 0; r < 4; ++r)
            op[r] = acc[r] + sRed[o + r] + sRed[320 + o + r] + sRed[640 + o + r];
    }

    // ---- split-K semaphore: release partial, 16th arriver finishes batch b ----
    __threadfence();                               // release wave-0's part writes
    __syncthreads();
    if (t == 0) {
        const unsigned old = atomicAdd(&ctr[b], 1u);
        sIsLast = (old == BLOCKS_PER_BATCH - 1) ? 1u : 0u;
    }
    __syncthreads();
    if (!sIsLast) return;
    __threadfence();                               // acquire other blocks' parts

    // ---- finish phase (same math as R5 soap_finish_kernel), LDS reused ----
    float* sE    = &sLds[0];                       // 256
    float* sPa   = &sLds[256];                     // 256 (ping)
    float* sPb   = &sLds[512];                     // 256 (pong)
    float* sG    = &sLds[768];                     // 256
    float* sWsum = &sLds[1024];                    // 4

    const int i = t >> 4, j = t & 15;

    // 1) reduce the 16 block partials, scale by 1/N
    float s = 0.0f;
#pragma unroll
    for (int c = 0; c < BLOCKS_PER_BATCH; ++c)
        s += part[((size_t)b * BLOCKS_PER_BATCH + c) * 256 + t];
    const float cov = s * (1.0f / (float)N_PTS);
    sE[t] = cov - ((i == j) ? 1.0f : 0.0f);        // E = cov - I

    // 2) matrix log via Horner, K=6 (||E|| <~ 0.07 => truncation ~5e-10)
    const int K = 6;
    sPa[t] = (i == j) ? (-1.0f / (float)K) : 0.0f;
    __syncthreads();
    float* cur = sPa;
    float* nxt = sPb;
    for (int k = K - 1; k >= 1; --k) {
        float q = 0.0f;
#pragma unroll
        for (int m = 0; m < 16; ++m) q += sE[i * 16 + m] * cur[m * 16 + j];
        const float ck = ((k & 1) ? 1.0f : -1.0f) / (float)k;
        if (i == j) q += ck;
        nxt[t] = q;                                // ping-pong: 1 barrier/iter
        __syncthreads();
        float* tmp = cur; cur = nxt; nxt = tmp;
    }
    float L = 0.0f;
#pragma unroll
    for (int m = 0; m < 16; ++m) L += sE[i * 16 + m] * cur[m * 16 + j];

    // 3) signed power normalization
    const float p = p_ptr[0];
    const float sgn = (L > 0.0f) ? 1.0f : ((L < 0.0f) ? -1.0f : 0.0f);
    sG[t] = sgn * powf(fabsf(L), p);
    __syncthreads();

    // 4) FC: f_t = b[t] + sum_k W[t,k] * g[k]
    const float4* __restrict__ W4 = (const float4*)W;
    float f = bias[t];
#pragma unroll 8
    for (int k = 0; k < 64; ++k) {
        const float4 w = W4[(size_t)t * 64 + k];
        f += w.x * sG[4 * k + 0] + w.y * sG[4 * k + 1]
           + w.z * sG[4 * k + 2] + w.w * sG[4 * k + 3];
    }

    // 5) L2 normalize across the 256 features
    float ss = f * f;
#pragma unroll
    for (int off = 32; off > 0; off >>= 1) ss += __shfl_down(ss, off, 64);
    if ((t & 63) == 0) sWsum[t >> 6] = ss;
    __syncthreads();
    const float tot = sWsum[0] + sWsum[1] + sWsum[2] + sWsum[3];
    const float nrm = fmaxf(sqrtf(tot), 1e-12f);
    out[(size_t)b * 256 + t] = f / nrm;
}

extern "C" void kernel_launch(void* const* d_in, const int* in_sizes, int n_in,
                              void* d_out, int out_size, void* d_ws, size_t ws_size,
                              hipStream_t stream) {
    (void)in_sizes; (void)n_in; (void)out_size; (void)ws_size;
    const float* x    = (const float*)d_in[0];
    const float* W    = (const float*)d_in[1];
    const float* bias = (const float*)d_in[2];
    const float* p    = (const float*)d_in[3];
    float* out  = (float*)d_out;
    float* part = (float*)d_ws;                           // 1 MB of partials
    unsigned int* ctr = (unsigned int*)((char*)d_ws + PART_FLOATS * sizeof(float));

    // workspace is re-poisoned every iteration -> counters must be zeroed here
    hipMemsetAsync(ctr, 0, B_BATCH * sizeof(unsigned int), stream);
    soap_fused_kernel<<<B_BATCH * BLOCKS_PER_BATCH, 256, 0, stream>>>(
        x, W, bias, p, part, ctr, out);
}

// Round 3
// 105.520 us; speedup vs baseline: 2.2272x; 2.2272x over previous
//
#include <hip/hip_runtime.h>
#include <hip/hip_bf16.h>
#include <math.h>

// SoAP: x[64,16384,16] -> cov[64,16,16] -> logm -> sign*|.|^p -> FC(256) -> L2 normalize
// R8: R7 with the compile fix: __exp2f/__log2f (CUDA names) -> raw gfx950 ops
//     __builtin_amdgcn_exp2f / __builtin_amdgcn_logf (v_exp_f32 / v_log_f32).
//     Structure: proven R5 two-kernel split; cov_mfma_kernel byte-identical to R5.
//     finish kernel: ping-pong Horner (6 barriers not 12, math validated in R6)
//     + hw pow: sgn * 2^(p * log2|L|).

#define B_BATCH 64
#define N_PTS   16384
#define BLOCKS_PER_BATCH 16
#define PTS_PER_WAVE 256
#define SLICE 2176                      // dwords per wave slice (128 pts, padded)

typedef short bf16x8 __attribute__((ext_vector_type(8)));
typedef float f32x4  __attribute__((ext_vector_type(4)));

__device__ __forceinline__ int lds_off(int p, int f) {   // p in [0,128), f in [0,16)
    return p * 16 + (p >> 3) * 8 + f;
}

__global__ __launch_bounds__(256, 4) void cov_mfma_kernel(
    const float* __restrict__ x, float* __restrict__ part)
{
    __shared__ float sLds[4 * SLICE];              // 34816 B, wave-private slices
    __shared__ float sRed[3 * 320];                // 3840 B
    const int t     = threadIdx.x;
    const int lane  = t & 63;
    const int wave  = t >> 6;
    const int b     = blockIdx.x >> 4;
    const int split = (blockIdx.x & 15) * 4 + wave;   // 0..63
    const int feat  = lane & 15;
    const int pgrp  = lane >> 4;

    const float4* __restrict__ xw = (const float4*)(x
        + ((size_t)b * N_PTS + (size_t)split * PTS_PER_WAVE) * 16);
    float* slice = &sLds[wave * SLICE];

    // issue all 16 linear 1-KB wave loads up front (16 KB in flight per wave)
    float4 reg[16];
#pragma unroll
    for (int j = 0; j < 16; ++j) reg[j] = xw[j * 64 + lane];

    f32x4 acc = {0.f, 0.f, 0.f, 0.f};

#pragma unroll
    for (int h = 0; h < 2; ++h) {
        // stage 128 points into the wave slice (b128 writes, 16B-aligned)
#pragma unroll
        for (int j = 0; j < 8; ++j) {
            const int q = j * 64 + lane;           // float4 index within half
            const int p = q >> 2, c = q & 3;
            *(float4*)&slice[lds_off(p, c * 4)] = reg[h * 8 + j];
        }
        // consume: 4 chunks of 32 points
#pragma unroll
        for (int c32 = 0; c32 < 4; ++c32) {
            bf16x8 H, L;
#pragma unroll
            for (int j = 0; j < 8; ++j) {
                const int p = c32 * 32 + pgrp * 8 + j;
                const float v = slice[lds_off(p, feat)];
                const unsigned u = __builtin_bit_cast(unsigned, v);
                H[j] = (short)(u >> 16);
                const float hf = __builtin_bit_cast(float, u & 0xFFFF0000u);
                const float lo = v - hf;
                L[j] = (short)(__builtin_bit_cast(unsigned, lo) >> 16);
            }
            acc = __builtin_amdgcn_mfma_f32_16x16x32_bf16(H, H, acc, 0, 0, 0);
            acc = __builtin_amdgcn_mfma_f32_16x16x32_bf16(H, L, acc, 0, 0, 0);
            acc = __builtin_amdgcn_mfma_f32_16x16x32_bf16(L, H, acc, 0, 0, 0);
        }
    }

    // intra-block reduction: waves 1..3 park acc, wave 0 sums and writes.
    // transposed (feat-major) store; cov symmetric so orientation is harmless.
    if (wave > 0) {
        float* sp = &sRed[(wave - 1) * 320 + feat * 20 + pgrp * 4];
#pragma unroll
        for (int r = 0; r < 4; ++r) sp[r] = acc[r];
    }
    __syncthreads();
    if (wave == 0) {
        float* op = part + (size_t)blockIdx.x * 256 + feat * 16 + pgrp * 4;
        const int o = feat * 20 + pgrp * 4;
#pragma unroll
        for (int r = 0; r < 4; ++r)
            op[r] = acc[r] + sRed[o + r] + sRed[320 + o + r] + sRed[640 + o + r];
    }
}

__global__ __launch_bounds__(256) void soap_finish_kernel(
    const float* __restrict__ part, const float* __restrict__ W,
    const float* __restrict__ bias, const float* __restrict__ p_ptr,
    float* __restrict__ out)
{
    __shared__ float sE[256];
    __shared__ float sPa[256];
    __shared__ float sPb[256];
    __shared__ float sG[256];
    __shared__ float sWsum[4];

    const int t = threadIdx.x;
    const int b = blockIdx.x;
    const int i = t >> 4, j = t & 15;

    // 1) reduce the 16 block partials, scale by 1/N
    float s = 0.0f;
#pragma unroll
    for (int c = 0; c < BLOCKS_PER_BATCH; ++c)
        s += part[((size_t)b * BLOCKS_PER_BATCH + c) * 256 + t];
    const float cov = s * (1.0f / (float)N_PTS);
    sE[t] = cov - ((i == j) ? 1.0f : 0.0f);      // E = cov - I

    // 2) matrix log via Horner, K=6 (||E|| <~ 0.07 => truncation ~5e-10)
    //    ping-pong buffers: 1 barrier per iteration (validated in R6, same absmax)
    const int K = 6;
    sPa[t] = (i == j) ? (-1.0f / (float)K) : 0.0f;
    __syncthreads();
    float* cur = sPa;
    float* nxt = sPb;
#pragma unroll
    for (int k = K - 1; k >= 1; --k) {
        float q = 0.0f;
#pragma unroll
        for (int m = 0; m < 16; ++m) q += sE[i * 16 + m] * cur[m * 16 + j];
        const float ck = ((k & 1) ? 1.0f : -1.0f) / (float)k;
        if (i == j) q += ck;
        nxt[t] = q;
        __syncthreads();
        float* tmp = cur; cur = nxt; nxt = tmp;
    }
    float L = 0.0f;
#pragma unroll
    for (int m = 0; m < 16; ++m) L += sE[i * 16 + m] * cur[m * 16 + j];

    // 3) signed power normalization: sgn(L)*|L|^p via hw exp2/log2
    //    (|L|=0 -> log2=-inf -> exp2=0, and sgn=0 anyway; err ~1e-6 << absmax)
    const float p = p_ptr[0];
    const float sgn = (L > 0.0f) ? 1.0f : ((L < 0.0f) ? -1.0f : 0.0f);
    sG[t] = sgn * __builtin_amdgcn_exp2f(p * __builtin_amdgcn_logf(fabsf(L)));
    __syncthreads();

    // 4) FC: f_t = b[t] + sum_k W[t,k] * g[k]
    const float4* __restrict__ W4 = (const float4*)W;
    float f = bias[t];
#pragma unroll 8
    for (int k = 0; k < 64; ++k) {
        const float4 w = W4[(size_t)t * 64 + k];
        f += w.x * sG[4 * k + 0] + w.y * sG[4 * k + 1]
           + w.z * sG[4 * k + 2] + w.w * sG[4 * k + 3];
    }

    // 5) L2 normalize across the 256 features
    float ss = f * f;
#pragma unroll
    for (int off = 32; off > 0; off >>= 1) ss += __shfl_down(ss, off, 64);
    if ((t & 63) == 0) sWsum[t >> 6] = ss;
    __syncthreads();
    const float tot = sWsum[0] + sWsum[1] + sWsum[2] + sWsum[3];
    const float nrm = fmaxf(sqrtf(tot), 1e-12f);
    out[(size_t)b * 256 + t] = f / nrm;
}

extern "C" void kernel_launch(void* const* d_in, const int* in_sizes, int n_in,
                              void* d_out, int out_size, void* d_ws, size_t ws_size,
                              hipStream_t stream) {
    (void)in_sizes; (void)n_in; (void)out_size; (void)ws_size;
    const float* x    = (const float*)d_in[0];
    const float* W    = (const float*)d_in[1];
    const float* bias = (const float*)d_in[2];
    const float* p    = (const float*)d_in[3];
    float* out  = (float*)d_out;
    float* part = (float*)d_ws;   // 1024 blocks * 256 floats = 1 MB

    cov_mfma_kernel<<<B_BATCH * BLOCKS_PER_BATCH, 256, 0, stream>>>(x, part);
    soap_finish_kernel<<<B_BATCH, 256, 0, stream>>>(part, W, bias, p, out);
}